// Round 10
// baseline (465.019 us; speedup 1.0000x reference)
//
#include <hip/hip_runtime.h>
#include <math.h>

#define TB 256
#define NB 32
#define NC 128
#define NHW 3136
#define ND 64
#define NT 49
#define KST 76   // Kb LDS row stride (f16); dword stride 38 -> odd-ish spread, b128-friendly
#define VST 74   // Vb LDS row stride (f16); dword stride 37 (odd) -> <=2-way b64 conflicts

typedef _Float16 half8 __attribute__((ext_vector_type(8)));
typedef _Float16 half4 __attribute__((ext_vector_type(4)));
typedef __fp16 fp16x2 __attribute__((ext_vector_type(2)));
typedef float float4v __attribute__((ext_vector_type(4)));

__device__ __forceinline__ void pack4h(_Float16* dst, float v0, float v1, float v2, float v3){
    union { fp16x2 h[2]; uint2 u; } pk;
    pk.h[0] = __builtin_amdgcn_cvt_pkrtz(v0, v1);
    pk.h[1] = __builtin_amdgcn_cvt_pkrtz(v2, v3);
    *(uint2*)dst = pk.u;
}
__device__ __forceinline__ half4 pack4v(float v0, float v1, float v2, float v3){
    union { fp16x2 h[2]; half4 v; } pk;
    pk.h[0] = __builtin_amdgcn_cvt_pkrtz(v0, v1);
    pk.h[1] = __builtin_amdgcn_cvt_pkrtz(v2, v3);
    return pk.v;
}

// ---------------- Kernel 0: weight prep (f16 transposes + w2b) ----------------
__global__ __launch_bounds__(TB) void k_prep(
    const float* __restrict__ We, const float* __restrict__ Wqkv,
    const float* __restrict__ Wp, const float* __restrict__ W1,
    const float* __restrict__ W2, const float* __restrict__ bm2,
    _Float16* __restrict__ WeT, _Float16* __restrict__ WqkvT,
    _Float16* __restrict__ WpT, _Float16* __restrict__ W1T,
    float* __restrict__ w2bx)
{
    const int t = blockIdx.x * TB + threadIdx.x;   // grid 8 -> 2048 threads
    for (int i = t; i < 8192;  i += 2048) WeT[i]   = (_Float16)We[(i & 127) * 64 + (i >> 7)];
    for (int i = t; i < 12288; i += 2048) WqkvT[i] = (_Float16)Wqkv[(i & 63) * 192 + (i >> 6)];
    for (int i = t; i < 4096;  i += 2048) WpT[i]   = (_Float16)Wp[(i & 63) * 64 + (i >> 6)];
    for (int i = t; i < 4096;  i += 2048) W1T[i]   = (_Float16)W1[(i & 63) * 64 + (i >> 6)];
    if (t < 64) {
        float s = 0.f;
        for (int d = 0; d < 64; ++d) s += W2[t * 64 + d];
        w2bx[t] = s * (1.f / 64.f);
    }
    if (t == 64) {
        float s = 0.f;
        for (int d = 0; d < 64; ++d) s += bm2[d];
        w2bx[64] = s * (1.f / 64.f);
    }
}

// ---------------- Kernel 1: embed + LN1 + LN2 + QKV (MFMA) ----------------
__global__ __launch_bounds__(TB) void k_embed_qkv(
    const float* __restrict__ x,    // [B][C][HW]
    const float* __restrict__ be,
    const float* __restrict__ g1, const float* __restrict__ b1,
    const float* __restrict__ g2, const float* __restrict__ b2,
    const float* __restrict__ bqkv,
    const _Float16* __restrict__ WeT,    // [64 d][128 c]
    const _Float16* __restrict__ WqkvT,  // [192 e][64 d]
    _Float16* __restrict__ qh, _Float16* __restrict__ khb, _Float16* __restrict__ vtb)
{
    __shared__ float xs[128 * 66];          // x tile [c][tok], stride 66
    __shared__ _Float16 zL[4 * 16 * 72];    // wave-private z slabs
    __shared__ _Float16 vt16[64 * 72];      // v^T tile [d][tok]

    const int b = blockIdx.y, n0 = blockIdx.x * 64, tid = threadIdx.x;
    const int w = tid >> 6, lane = tid & 63, quad = lane >> 4, cl = lane & 15;

    // stage x tile
    {
        const int cb = tid >> 4, tok4 = (tid & 15) * 4;
        const float* xb = x + (size_t)b * NC * NHW + n0 + tok4;
        #pragma unroll
        for (int p = 0; p < 8; ++p) {
            const int c = p * 16 + cb;
            float4 v = *(const float4*)(xb + (size_t)c * NHW);
            float* dst = &xs[c * 66 + tok4];
            *(float2*)dst = make_float2(v.x, v.y);
            *(float2*)(dst + 2) = make_float2(v.z, v.w);
        }
    }
    __syncthreads();

    // B-frags of x^T
    half8 bx[4];
    #pragma unroll
    for (int ck = 0; ck < 4; ++ck) {
        const float* xp = &xs[(ck * 32 + quad * 8) * 66 + w * 16 + cl];
        union { fp16x2 h[4]; half8 v; } u;
        #pragma unroll
        for (int jj = 0; jj < 4; ++jj)
            u.h[jj] = __builtin_amdgcn_cvt_pkrtz(xp[(2 * jj) * 66], xp[(2 * jj + 1) * 66]);
        bx[ck] = u.v;
    }

    // t^T = WeT @ x^T, bias in acc init
    float tv[4][4];
    #pragma unroll
    for (int dt = 0; dt < 4; ++dt) {
        float4 bev = *(const float4*)(be + dt * 16 + quad * 4);
        float4v acc = (float4v){bev.x, bev.y, bev.z, bev.w};
        #pragma unroll
        for (int ck = 0; ck < 4; ++ck) {
            half8 af = *(const half8*)(WeT + (dt * 16 + cl) * 128 + ck * 32 + quad * 8);
            acc = __builtin_amdgcn_mfma_f32_16x16x32_f16(af, bx[ck], acc, 0, 0, 0);
        }
        #pragma unroll
        for (int r = 0; r < 4; ++r) tv[dt][r] = acc[r];
    }

    // double LayerNorm, in-lane
    #pragma unroll
    for (int ln = 0; ln < 2; ++ln) {
        float sm = 0.f;
        #pragma unroll
        for (int dt = 0; dt < 4; ++dt)
            #pragma unroll
            for (int r = 0; r < 4; ++r) sm += tv[dt][r];
        sm += __shfl_xor(sm, 16); sm += __shfl_xor(sm, 32);
        const float mu = sm * (1.f / 64.f);
        float vr = 0.f;
        #pragma unroll
        for (int dt = 0; dt < 4; ++dt)
            #pragma unroll
            for (int r = 0; r < 4; ++r) { float d = tv[dt][r] - mu; vr += d * d; }
        vr += __shfl_xor(vr, 16); vr += __shfl_xor(vr, 32);
        const float is = rsqrtf(vr * (1.f / 64.f) + 1e-5f);
        const float* gp = (ln == 0) ? g1 : g2;
        const float* bp_ = (ln == 0) ? b1 : b2;
        #pragma unroll
        for (int dt = 0; dt < 4; ++dt) {
            float4 gq = *(const float4*)(gp + dt * 16 + quad * 4);
            float4 bq = *(const float4*)(bp_ + dt * 16 + quad * 4);
            const float* gqp = (const float*)&gq;
            const float* bqp = (const float*)&bq;
            #pragma unroll
            for (int r = 0; r < 4; ++r)
                tv[dt][r] = (tv[dt][r] - mu) * is * gqp[r] + bqp[r];
        }
    }

    // stage z wave-private; B-frags
    _Float16* zw = zL + w * (16 * 72);
    #pragma unroll
    for (int dt = 0; dt < 4; ++dt)
        *(half4*)&zw[cl * 72 + dt * 16 + quad * 4] = pack4v(tv[dt][0], tv[dt][1], tv[dt][2], tv[dt][3]);
    __asm__ __volatile__("s_waitcnt lgkmcnt(0)" ::: "memory");
    half8 bz[2];
    #pragma unroll
    for (int ck = 0; ck < 2; ++ck)
        bz[ck] = *(const half8*)&zw[cl * 72 + ck * 32 + quad * 8];

    // qkv^T = WqkvT @ z^T (bias in acc); q scaled by 0.125*log2e
    const float QSC = 0.125f * 1.44269504088896f;
    const int tok = w * 16 + cl;
    #pragma unroll
    for (int et = 0; et < 12; ++et) {
        float4 bq = *(const float4*)(bqkv + et * 16 + quad * 4);
        float4v acc = (float4v){bq.x, bq.y, bq.z, bq.w};
        #pragma unroll
        for (int ck = 0; ck < 2; ++ck) {
            half8 af = *(const half8*)(WqkvT + (et * 16 + cl) * 64 + ck * 32 + quad * 8);
            acc = __builtin_amdgcn_mfma_f32_16x16x32_f16(af, bz[ck], acc, 0, 0, 0);
        }
        if (et < 4) {
            pack4h(qh + ((size_t)(b * NHW + n0 + tok)) * ND + et * 16 + quad * 4,
                   acc[0] * QSC, acc[1] * QSC, acc[2] * QSC, acc[3] * QSC);
        } else if (et < 8) {
            pack4h(khb + ((size_t)(b * NHW + n0 + tok)) * ND + (et - 4) * 16 + quad * 4,
                   acc[0], acc[1], acc[2], acc[3]);
        } else {
            #pragma unroll
            for (int r = 0; r < 4; ++r)
                vt16[((et - 8) * 16 + quad * 4 + r) * 72 + tok] = (_Float16)acc[r];
        }
    }
    __syncthreads();
    #pragma unroll
    for (int i = 0; i < 2; ++i) {
        int ch = tid + 256 * i;
        int row = ch >> 3, off = (ch & 7) * 8;
        *(uint4*)(vtb + ((size_t)(b * ND + row)) * NHW + n0 + off) =
            *(const uint4*)&vt16[row * 72 + off];
    }
}

// ---------------- Kernel 2: MFMA flash attention ----------------
// grid (25, 32): tile on fast axis, b = blockIdx.y -- R7's mapping.
// R8/R9 showed the batch-on-fast-axis XCD swizzle cost 130us (FETCH dropped
// 4x but same-batch block co-residency/L1 phase-locking was worth far more).
// Two-barrier double-buffered K-loop (R7-proven; single-barrier was neutral).
__global__ __launch_bounds__(TB) void k_attn(
    const _Float16* __restrict__ qh, const _Float16* __restrict__ khb,
    const _Float16* __restrict__ vtb, _Float16* __restrict__ ob)
{
    __shared__ _Float16 Kb[2][64 * KST];   // K[key][d]
    __shared__ _Float16 Vb[2][64 * VST];   // V^T[d][key]

    const int b    = blockIdx.y;
    const int n0   = blockIdx.x * 128;
    const int tid  = threadIdx.x;
    const int w    = tid >> 6;
    const int lane = tid & 63;
    const int quad = lane >> 4;
    const int c    = lane & 15;
    const float CEXP = 4.0f * 1.44269504088896f;   // fixed softmax shift (4 nats)

    // Q fragments (B-operand, 16x16x32)
    half8 qf[2][2];
    #pragma unroll
    for (int qt = 0; qt < 2; ++qt) {
        int row = n0 + w * 32 + qt * 16 + c;
        row = row < NHW ? row : NHW - 1;
        const _Float16* qp = qh + ((size_t)(b * NHW + row)) * ND + quad * 8;
        qf[qt][0] = *(const half8*)(qp);
        qf[qt][1] = *(const half8*)(qp + 32);
    }

    float4v o[2][4];
    #pragma unroll
    for (int qt = 0; qt < 2; ++qt)
        #pragma unroll
        for (int nt = 0; nt < 4; ++nt) o[qt][nt] = (float4v){0.f, 0.f, 0.f, 0.f};
    float lp[2] = {0.f, 0.f};

    const _Float16* kbase = khb + ((size_t)b * NHW) * ND;
    const _Float16* vbase = vtb + ((size_t)b * ND) * NHW;

    const int row0 = (tid + 0)   >> 3, off0 = ((tid + 0)   & 7) * 8;
    const int row1 = (tid + 256) >> 3, off1 = ((tid + 256) & 7) * 8;

    uint4 pk0, pk1, pv0, pv1;
    pk0 = *(const uint4*)(kbase + (size_t)row0 * ND + off0);
    pk1 = *(const uint4*)(kbase + (size_t)row1 * ND + off1);
    pv0 = *(const uint4*)(vbase + (size_t)row0 * NHW + off0);
    pv1 = *(const uint4*)(vbase + (size_t)row1 * NHW + off1);

    for (int kt = 0; kt < NT; ++kt) {
        const int bsel = kt & 1;
        __syncthreads();   // (A) all waves finished reading buf[bsel] (step kt-2)
        *(uint4*)&Kb[bsel][row0 * KST + off0] = pk0;
        *(uint4*)&Kb[bsel][row1 * KST + off1] = pk1;
        *(uint4*)&Vb[bsel][row0 * VST + off0] = pv0;
        *(uint4*)&Vb[bsel][row1 * VST + off1] = pv1;
        if (kt + 1 < NT) {
            const _Float16* kp = kbase + (size_t)((kt + 1) * 64) * ND;
            const _Float16* vp = vbase + (kt + 1) * 64;
            pk0 = *(const uint4*)(kp + (size_t)row0 * ND + off0);
            pk1 = *(const uint4*)(kp + (size_t)row1 * ND + off1);
            pv0 = *(const uint4*)(vp + (size_t)row0 * NHW + off0);
            pv1 = *(const uint4*)(vp + (size_t)row1 * NHW + off1);
        }
        __syncthreads();   // (B) buf[bsel] writes visible

        // K A-fragments
        half8 ka[4][2];
        #pragma unroll
        for (int mt = 0; mt < 4; ++mt) {
            const _Float16* kp = &Kb[bsel][(mt * 16 + c) * KST + quad * 8];
            ka[mt][0] = *(const half8*)(kp);
            ka[mt][1] = *(const half8*)(kp + 32);
        }

        // S^T = K @ Q^T, acc pre-loaded with -CEXP (softmax shift for free)
        float4v s[2][4];
        #pragma unroll
        for (int qt = 0; qt < 2; ++qt)
            #pragma unroll
            for (int mt = 0; mt < 4; ++mt) {
                float4v z = (float4v){-CEXP, -CEXP, -CEXP, -CEXP};
                z = __builtin_amdgcn_mfma_f32_16x16x32_f16(ka[mt][0], qf[qt][0], z, 0, 0, 0);
                z = __builtin_amdgcn_mfma_f32_16x16x32_f16(ka[mt][1], qf[qt][1], z, 0, 0, 0);
                s[qt][mt] = z;
            }

        // p = exp2(s); accumulate per-lane l; pack P
        half4 pb[2][4];
        #pragma unroll
        for (int qt = 0; qt < 2; ++qt) {
            float ls = 0.f;
            #pragma unroll
            for (int mt = 0; mt < 4; ++mt) {
                #pragma unroll
                for (int r = 0; r < 4; ++r) {
                    float p = __builtin_amdgcn_exp2f(s[qt][mt][r]);
                    s[qt][mt][r] = p;
                    ls += p;
                }
                pb[qt][mt] = pack4v(s[qt][mt][0], s[qt][mt][1], s[qt][mt][2], s[qt][mt][3]);
            }
            lp[qt] += ls;
        }

        // O^T += V^T @ P^T  (16x16x16)
        #pragma unroll
        for (int nt = 0; nt < 4; ++nt) {
            #pragma unroll
            for (int mt = 0; mt < 4; ++mt) {
                half4 vv = *(const half4*)&Vb[bsel][(nt * 16 + c) * VST + mt * 16 + quad * 4];
                #pragma unroll
                for (int qt = 0; qt < 2; ++qt)
                    o[qt][nt] = __builtin_amdgcn_mfma_f32_16x16x16f16(vv, pb[qt][mt], o[qt][nt], 0, 0, 0);
            }
        }
    }

    // epilogue
    #pragma unroll
    for (int qt = 0; qt < 2; ++qt) {
        float lq = lp[qt];
        lq += __shfl_xor(lq, 16); lq += __shfl_xor(lq, 32);
        float inv = 1.f / lq;
        int row = n0 + w * 32 + qt * 16 + c;
        if (row < NHW) {
            _Float16* op = ob + ((size_t)(b * NHW + row)) * ND + quad * 4;
            #pragma unroll
            for (int nt = 0; nt < 4; ++nt)
                pack4h(op + nt * 16, o[qt][nt][0] * inv, o[qt][nt][1] * inv,
                       o[qt][nt][2] * inv, o[qt][nt][3] * inv);
        }
    }
}

// ---------------- Kernel 3: proj + LN + MLP(gelu) + channel-mean (MFMA) ----------------
__global__ __launch_bounds__(TB) void k_post(
    const _Float16* __restrict__ aih,   // attn out f16 [B][N][64]
    const float* __restrict__ bp,
    const float* __restrict__ gm, const float* __restrict__ bm,
    const float* __restrict__ bm1,
    const _Float16* __restrict__ WpT, const _Float16* __restrict__ W1T,
    const float* __restrict__ w2bx,     // [65]: w2b + bm2b
    float* __restrict__ out)
{
    __shared__ _Float16 zL2[4 * 16 * 72];

    const int b = blockIdx.y, n0 = blockIdx.x * 64, tid = threadIdx.x;
    const int w = tid >> 6, lane = tid & 63, quad = lane >> 4, cl = lane & 15;
    const int tok = w * 16 + cl;

    const _Float16* ap = aih + ((size_t)(b * NHW + n0 + tok)) * ND;
    half8 ba[2];
    ba[0] = *(const half8*)(ap + quad * 8);
    ba[1] = *(const half8*)(ap + 32 + quad * 8);

    // u^T = WpT @ A^T (bias in acc)
    float uv[4][4];
    #pragma unroll
    for (int et = 0; et < 4; ++et) {
        float4 bq = *(const float4*)(bp + et * 16 + quad * 4);
        float4v acc = (float4v){bq.x, bq.y, bq.z, bq.w};
        #pragma unroll
        for (int ck = 0; ck < 2; ++ck) {
            half8 af = *(const half8*)(WpT + (et * 16 + cl) * 64 + ck * 32 + quad * 8);
            acc = __builtin_amdgcn_mfma_f32_16x16x32_f16(af, ba[ck], acc, 0, 0, 0);
        }
        #pragma unroll
        for (int r = 0; r < 4; ++r) uv[et][r] = acc[r];
    }

    // LayerNorm (gm, bm), in-lane
    {
        float sm = 0.f;
        #pragma unroll
        for (int et = 0; et < 4; ++et)
            #pragma unroll
            for (int r = 0; r < 4; ++r) sm += uv[et][r];
        sm += __shfl_xor(sm, 16); sm += __shfl_xor(sm, 32);
        const float mu = sm * (1.f / 64.f);
        float vr = 0.f;
        #pragma unroll
        for (int et = 0; et < 4; ++et)
            #pragma unroll
            for (int r = 0; r < 4; ++r) { float d = uv[et][r] - mu; vr += d * d; }
        vr += __shfl_xor(vr, 16); vr += __shfl_xor(vr, 32);
        const float is = rsqrtf(vr * (1.f / 64.f) + 1e-5f);
        #pragma unroll
        for (int et = 0; et < 4; ++et) {
            float4 gq = *(const float4*)(gm + et * 16 + quad * 4);
            float4 bq = *(const float4*)(bm + et * 16 + quad * 4);
            const float* gqp = (const float*)&gq;
            const float* bqp = (const float*)&bq;
            #pragma unroll
            for (int r = 0; r < 4; ++r)
                uv[et][r] = (uv[et][r] - mu) * is * gqp[r] + bqp[r];
        }
    }

    // stage z2 wave-private; B-frags
    _Float16* zw = zL2 + w * (16 * 72);
    #pragma unroll
    for (int et = 0; et < 4; ++et)
        *(half4*)&zw[cl * 72 + et * 16 + quad * 4] = pack4v(uv[et][0], uv[et][1], uv[et][2], uv[et][3]);
    __asm__ __volatile__("s_waitcnt lgkmcnt(0)" ::: "memory");
    half8 bz[2];
    #pragma unroll
    for (int ck = 0; ck < 2; ++ck)
        bz[ck] = *(const half8*)&zw[cl * 72 + ck * 32 + quad * 8];

    // h^T = W1T @ z2^T + bm1; gelu; dot with w2b; reduce
    float part = 0.f;
    #pragma unroll
    for (int et = 0; et < 4; ++et) {
        float4 b1q = *(const float4*)(bm1 + et * 16 + quad * 4);
        float4v acc = (float4v){b1q.x, b1q.y, b1q.z, b1q.w};
        #pragma unroll
        for (int ck = 0; ck < 2; ++ck) {
            half8 af = *(const half8*)(W1T + (et * 16 + cl) * 64 + ck * 32 + quad * 8);
            acc = __builtin_amdgcn_mfma_f32_16x16x32_f16(af, bz[ck], acc, 0, 0, 0);
        }
        float4 wq = *(const float4*)(w2bx + et * 16 + quad * 4);
        const float* wqp = (const float*)&wq;
        #pragma unroll
        for (int r = 0; r < 4; ++r) {
            float h = acc[r];
            float g = 0.5f * h * (1.f + erff(h * 0.70710678118654752f));
            part = fmaf(g, wqp[r], part);
        }
    }
    part += __shfl_xor(part, 16); part += __shfl_xor(part, 32);
    if (lane < 16)
        out[(size_t)b * NHW + n0 + tok] = part + w2bx[64];
}

extern "C" void kernel_launch(void* const* d_in, const int* in_sizes, int n_in,
                              void* d_out, int out_size, void* d_ws, size_t ws_size,
                              hipStream_t stream) {
    (void)in_sizes; (void)n_in; (void)out_size; (void)ws_size;
    const float* x    = (const float*)d_in[0];
    const float* We   = (const float*)d_in[1];
    const float* be   = (const float*)d_in[2];
    const float* g1   = (const float*)d_in[3];
    const float* b1   = (const float*)d_in[4];
    const float* g2   = (const float*)d_in[5];
    const float* b2   = (const float*)d_in[6];
    const float* Wqkv = (const float*)d_in[7];
    const float* bqkv = (const float*)d_in[8];
    const float* Wp   = (const float*)d_in[9];
    const float* bp   = (const float*)d_in[10];
    const float* gm   = (const float*)d_in[11];
    const float* bm   = (const float*)d_in[12];
    const float* W1   = (const float*)d_in[13];
    const float* bm1  = (const float*)d_in[14];
    const float* W2   = (const float*)d_in[15];
    const float* bm2  = (const float*)d_in[16];
    float* out = (float*)d_out;

    const size_t NQ = (size_t)NB * NHW * ND;
    _Float16* qh    = (_Float16*)d_ws;
    _Float16* khb   = qh + NQ;
    _Float16* vtb   = khb + NQ;
    _Float16* obf   = vtb + NQ;
    _Float16* WeT   = obf + NQ;
    _Float16* WqkvT = WeT + 64 * 128;
    _Float16* WpT   = WqkvT + 192 * 64;
    _Float16* W1T   = WpT + 64 * 64;
    float*    w2bx  = (float*)(W1T + 64 * 64);

    dim3 blk(TB);
    k_prep<<<dim3(8), blk, 0, stream>>>(We, Wqkv, Wp, W1, W2, bm2, WeT, WqkvT, WpT, W1T, w2bx);
    k_embed_qkv<<<dim3(NT, NB), blk, 0, stream>>>(x, be, g1, b1, g2, b2, bqkv, WeT, WqkvT, qh, khb, vtb);
    k_attn<<<dim3(25, NB), blk, 0, stream>>>(qh, khb, vtb, obf);
    k_post<<<dim3(NT, NB), blk, 0, stream>>>(obf, bp, gm, bm, bm1, WpT, W1T, w2bx, out);
}

// Round 11
// 318.551 us; speedup vs baseline: 1.4598x; 1.4598x over previous
//
#include <hip/hip_runtime.h>
#include <math.h>

#define TB 256
#define NB 32
#define NC 128
#define NHW 3136
#define ND 64
#define NT 49
#define KST 72   // 144 B rows: 16B-aligned -> single ds_read_b128/ds_write_b128.
#define VST 72   // 76/74 (R8-R10) broke 16B alignment -> split LDS ops, 180->310us.

typedef _Float16 half8 __attribute__((ext_vector_type(8)));
typedef _Float16 half4 __attribute__((ext_vector_type(4)));
typedef __fp16 fp16x2 __attribute__((ext_vector_type(2)));
typedef float float4v __attribute__((ext_vector_type(4)));

__device__ __forceinline__ void pack4h(_Float16* dst, float v0, float v1, float v2, float v3){
    union { fp16x2 h[2]; uint2 u; } pk;
    pk.h[0] = __builtin_amdgcn_cvt_pkrtz(v0, v1);
    pk.h[1] = __builtin_amdgcn_cvt_pkrtz(v2, v3);
    *(uint2*)dst = pk.u;
}
__device__ __forceinline__ half4 pack4v(float v0, float v1, float v2, float v3){
    union { fp16x2 h[2]; half4 v; } pk;
    pk.h[0] = __builtin_amdgcn_cvt_pkrtz(v0, v1);
    pk.h[1] = __builtin_amdgcn_cvt_pkrtz(v2, v3);
    return pk.v;
}

// ---------------- Kernel 0: weight prep (f16 transposes + w2b) ----------------
__global__ __launch_bounds__(TB) void k_prep(
    const float* __restrict__ We, const float* __restrict__ Wqkv,
    const float* __restrict__ Wp, const float* __restrict__ W1,
    const float* __restrict__ W2, const float* __restrict__ bm2,
    _Float16* __restrict__ WeT, _Float16* __restrict__ WqkvT,
    _Float16* __restrict__ WpT, _Float16* __restrict__ W1T,
    float* __restrict__ w2bx)
{
    const int t = blockIdx.x * TB + threadIdx.x;   // grid 8 -> 2048 threads
    for (int i = t; i < 8192;  i += 2048) WeT[i]   = (_Float16)We[(i & 127) * 64 + (i >> 7)];
    for (int i = t; i < 12288; i += 2048) WqkvT[i] = (_Float16)Wqkv[(i & 63) * 192 + (i >> 6)];
    for (int i = t; i < 4096;  i += 2048) WpT[i]   = (_Float16)Wp[(i & 63) * 64 + (i >> 6)];
    for (int i = t; i < 4096;  i += 2048) W1T[i]   = (_Float16)W1[(i & 63) * 64 + (i >> 6)];
    if (t < 64) {
        float s = 0.f;
        for (int d = 0; d < 64; ++d) s += W2[t * 64 + d];
        w2bx[t] = s * (1.f / 64.f);
    }
    if (t == 64) {
        float s = 0.f;
        for (int d = 0; d < 64; ++d) s += bm2[d];
        w2bx[64] = s * (1.f / 64.f);
    }
}

// ---------------- Kernel 1: embed + LN1 + LN2 + QKV (MFMA) ----------------
__global__ __launch_bounds__(TB) void k_embed_qkv(
    const float* __restrict__ x,    // [B][C][HW]
    const float* __restrict__ be,
    const float* __restrict__ g1, const float* __restrict__ b1,
    const float* __restrict__ g2, const float* __restrict__ b2,
    const float* __restrict__ bqkv,
    const _Float16* __restrict__ WeT,    // [64 d][128 c]
    const _Float16* __restrict__ WqkvT,  // [192 e][64 d]
    _Float16* __restrict__ qh, _Float16* __restrict__ khb, _Float16* __restrict__ vtb)
{
    __shared__ float xs[128 * 66];          // x tile [c][tok], stride 66
    __shared__ _Float16 zL[4 * 16 * 72];    // wave-private z slabs
    __shared__ _Float16 vt16[64 * 72];      // v^T tile [d][tok]

    const int b = blockIdx.y, n0 = blockIdx.x * 64, tid = threadIdx.x;
    const int w = tid >> 6, lane = tid & 63, quad = lane >> 4, cl = lane & 15;

    // stage x tile
    {
        const int cb = tid >> 4, tok4 = (tid & 15) * 4;
        const float* xb = x + (size_t)b * NC * NHW + n0 + tok4;
        #pragma unroll
        for (int p = 0; p < 8; ++p) {
            const int c = p * 16 + cb;
            float4 v = *(const float4*)(xb + (size_t)c * NHW);
            float* dst = &xs[c * 66 + tok4];
            *(float2*)dst = make_float2(v.x, v.y);
            *(float2*)(dst + 2) = make_float2(v.z, v.w);
        }
    }
    __syncthreads();

    // B-frags of x^T
    half8 bx[4];
    #pragma unroll
    for (int ck = 0; ck < 4; ++ck) {
        const float* xp = &xs[(ck * 32 + quad * 8) * 66 + w * 16 + cl];
        union { fp16x2 h[4]; half8 v; } u;
        #pragma unroll
        for (int jj = 0; jj < 4; ++jj)
            u.h[jj] = __builtin_amdgcn_cvt_pkrtz(xp[(2 * jj) * 66], xp[(2 * jj + 1) * 66]);
        bx[ck] = u.v;
    }

    // t^T = WeT @ x^T, bias in acc init
    float tv[4][4];
    #pragma unroll
    for (int dt = 0; dt < 4; ++dt) {
        float4 bev = *(const float4*)(be + dt * 16 + quad * 4);
        float4v acc = (float4v){bev.x, bev.y, bev.z, bev.w};
        #pragma unroll
        for (int ck = 0; ck < 4; ++ck) {
            half8 af = *(const half8*)(WeT + (dt * 16 + cl) * 128 + ck * 32 + quad * 8);
            acc = __builtin_amdgcn_mfma_f32_16x16x32_f16(af, bx[ck], acc, 0, 0, 0);
        }
        #pragma unroll
        for (int r = 0; r < 4; ++r) tv[dt][r] = acc[r];
    }

    // double LayerNorm, in-lane
    #pragma unroll
    for (int ln = 0; ln < 2; ++ln) {
        float sm = 0.f;
        #pragma unroll
        for (int dt = 0; dt < 4; ++dt)
            #pragma unroll
            for (int r = 0; r < 4; ++r) sm += tv[dt][r];
        sm += __shfl_xor(sm, 16); sm += __shfl_xor(sm, 32);
        const float mu = sm * (1.f / 64.f);
        float vr = 0.f;
        #pragma unroll
        for (int dt = 0; dt < 4; ++dt)
            #pragma unroll
            for (int r = 0; r < 4; ++r) { float d = tv[dt][r] - mu; vr += d * d; }
        vr += __shfl_xor(vr, 16); vr += __shfl_xor(vr, 32);
        const float is = rsqrtf(vr * (1.f / 64.f) + 1e-5f);
        const float* gp = (ln == 0) ? g1 : g2;
        const float* bp_ = (ln == 0) ? b1 : b2;
        #pragma unroll
        for (int dt = 0; dt < 4; ++dt) {
            float4 gq = *(const float4*)(gp + dt * 16 + quad * 4);
            float4 bq = *(const float4*)(bp_ + dt * 16 + quad * 4);
            const float* gqp = (const float*)&gq;
            const float* bqp = (const float*)&bq;
            #pragma unroll
            for (int r = 0; r < 4; ++r)
                tv[dt][r] = (tv[dt][r] - mu) * is * gqp[r] + bqp[r];
        }
    }

    // stage z wave-private; B-frags
    _Float16* zw = zL + w * (16 * 72);
    #pragma unroll
    for (int dt = 0; dt < 4; ++dt)
        *(half4*)&zw[cl * 72 + dt * 16 + quad * 4] = pack4v(tv[dt][0], tv[dt][1], tv[dt][2], tv[dt][3]);
    __asm__ __volatile__("s_waitcnt lgkmcnt(0)" ::: "memory");
    half8 bz[2];
    #pragma unroll
    for (int ck = 0; ck < 2; ++ck)
        bz[ck] = *(const half8*)&zw[cl * 72 + ck * 32 + quad * 8];

    // qkv^T = WqkvT @ z^T (bias in acc); q scaled by 0.125*log2e
    const float QSC = 0.125f * 1.44269504088896f;
    const int tok = w * 16 + cl;
    #pragma unroll
    for (int et = 0; et < 12; ++et) {
        float4 bq = *(const float4*)(bqkv + et * 16 + quad * 4);
        float4v acc = (float4v){bq.x, bq.y, bq.z, bq.w};
        #pragma unroll
        for (int ck = 0; ck < 2; ++ck) {
            half8 af = *(const half8*)(WqkvT + (et * 16 + cl) * 64 + ck * 32 + quad * 8);
            acc = __builtin_amdgcn_mfma_f32_16x16x32_f16(af, bz[ck], acc, 0, 0, 0);
        }
        if (et < 4) {
            pack4h(qh + ((size_t)(b * NHW + n0 + tok)) * ND + et * 16 + quad * 4,
                   acc[0] * QSC, acc[1] * QSC, acc[2] * QSC, acc[3] * QSC);
        } else if (et < 8) {
            pack4h(khb + ((size_t)(b * NHW + n0 + tok)) * ND + (et - 4) * 16 + quad * 4,
                   acc[0], acc[1], acc[2], acc[3]);
        } else {
            #pragma unroll
            for (int r = 0; r < 4; ++r)
                vt16[((et - 8) * 16 + quad * 4 + r) * 72 + tok] = (_Float16)acc[r];
        }
    }
    __syncthreads();
    #pragma unroll
    for (int i = 0; i < 2; ++i) {
        int ch = tid + 256 * i;
        int row = ch >> 3, off = (ch & 7) * 8;
        *(uint4*)(vtb + ((size_t)(b * ND + row)) * NHW + n0 + off) =
            *(const uint4*)&vt16[row * 72 + off];
    }
}

// ---------------- Kernel 2: MFMA flash attention ----------------
// grid (25, 32): tile on fast axis, b = blockIdx.y (R7 mapping).
// Two-barrier double-buffered K-loop (R7-proven). LDS row stride 72
// (144 B, 16B-aligned) -- REQUIRED for single-instruction b128/b64 LDS ops.
__global__ __launch_bounds__(TB) void k_attn(
    const _Float16* __restrict__ qh, const _Float16* __restrict__ khb,
    const _Float16* __restrict__ vtb, _Float16* __restrict__ ob)
{
    __shared__ _Float16 Kb[2][64 * KST];   // K[key][d]
    __shared__ _Float16 Vb[2][64 * VST];   // V^T[d][key]

    const int b    = blockIdx.y;
    const int n0   = blockIdx.x * 128;
    const int tid  = threadIdx.x;
    const int w    = tid >> 6;
    const int lane = tid & 63;
    const int quad = lane >> 4;
    const int c    = lane & 15;
    const float CEXP = 4.0f * 1.44269504088896f;   // fixed softmax shift (4 nats)

    // Q fragments (B-operand, 16x16x32)
    half8 qf[2][2];
    #pragma unroll
    for (int qt = 0; qt < 2; ++qt) {
        int row = n0 + w * 32 + qt * 16 + c;
        row = row < NHW ? row : NHW - 1;
        const _Float16* qp = qh + ((size_t)(b * NHW + row)) * ND + quad * 8;
        qf[qt][0] = *(const half8*)(qp);
        qf[qt][1] = *(const half8*)(qp + 32);
    }

    float4v o[2][4];
    #pragma unroll
    for (int qt = 0; qt < 2; ++qt)
        #pragma unroll
        for (int nt = 0; nt < 4; ++nt) o[qt][nt] = (float4v){0.f, 0.f, 0.f, 0.f};
    float lp[2] = {0.f, 0.f};

    const _Float16* kbase = khb + ((size_t)b * NHW) * ND;
    const _Float16* vbase = vtb + ((size_t)b * ND) * NHW;

    const int row0 = (tid + 0)   >> 3, off0 = ((tid + 0)   & 7) * 8;
    const int row1 = (tid + 256) >> 3, off1 = ((tid + 256) & 7) * 8;

    uint4 pk0, pk1, pv0, pv1;
    pk0 = *(const uint4*)(kbase + (size_t)row0 * ND + off0);
    pk1 = *(const uint4*)(kbase + (size_t)row1 * ND + off1);
    pv0 = *(const uint4*)(vbase + (size_t)row0 * NHW + off0);
    pv1 = *(const uint4*)(vbase + (size_t)row1 * NHW + off1);

    for (int kt = 0; kt < NT; ++kt) {
        const int bsel = kt & 1;
        __syncthreads();   // (A) all waves finished reading buf[bsel] (step kt-2)
        *(uint4*)&Kb[bsel][row0 * KST + off0] = pk0;
        *(uint4*)&Kb[bsel][row1 * KST + off1] = pk1;
        *(uint4*)&Vb[bsel][row0 * VST + off0] = pv0;
        *(uint4*)&Vb[bsel][row1 * VST + off1] = pv1;
        if (kt + 1 < NT) {
            const _Float16* kp = kbase + (size_t)((kt + 1) * 64) * ND;
            const _Float16* vp = vbase + (kt + 1) * 64;
            pk0 = *(const uint4*)(kp + (size_t)row0 * ND + off0);
            pk1 = *(const uint4*)(kp + (size_t)row1 * ND + off1);
            pv0 = *(const uint4*)(vp + (size_t)row0 * NHW + off0);
            pv1 = *(const uint4*)(vp + (size_t)row1 * NHW + off1);
        }
        __syncthreads();   // (B) buf[bsel] writes visible

        // K A-fragments
        half8 ka[4][2];
        #pragma unroll
        for (int mt = 0; mt < 4; ++mt) {
            const _Float16* kp = &Kb[bsel][(mt * 16 + c) * KST + quad * 8];
            ka[mt][0] = *(const half8*)(kp);
            ka[mt][1] = *(const half8*)(kp + 32);
        }

        // S^T = K @ Q^T, acc pre-loaded with -CEXP (softmax shift for free)
        float4v s[2][4];
        #pragma unroll
        for (int qt = 0; qt < 2; ++qt)
            #pragma unroll
            for (int mt = 0; mt < 4; ++mt) {
                float4v z = (float4v){-CEXP, -CEXP, -CEXP, -CEXP};
                z = __builtin_amdgcn_mfma_f32_16x16x32_f16(ka[mt][0], qf[qt][0], z, 0, 0, 0);
                z = __builtin_amdgcn_mfma_f32_16x16x32_f16(ka[mt][1], qf[qt][1], z, 0, 0, 0);
                s[qt][mt] = z;
            }

        // p = exp2(s); accumulate per-lane l; pack P
        half4 pb[2][4];
        #pragma unroll
        for (int qt = 0; qt < 2; ++qt) {
            float ls = 0.f;
            #pragma unroll
            for (int mt = 0; mt < 4; ++mt) {
                #pragma unroll
                for (int r = 0; r < 4; ++r) {
                    float p = __builtin_amdgcn_exp2f(s[qt][mt][r]);
                    s[qt][mt][r] = p;
                    ls += p;
                }
                pb[qt][mt] = pack4v(s[qt][mt][0], s[qt][mt][1], s[qt][mt][2], s[qt][mt][3]);
            }
            lp[qt] += ls;
        }

        // O^T += V^T @ P^T  (16x16x16)
        #pragma unroll
        for (int nt = 0; nt < 4; ++nt) {
            #pragma unroll
            for (int mt = 0; mt < 4; ++mt) {
                half4 vv = *(const half4*)&Vb[bsel][(nt * 16 + c) * VST + mt * 16 + quad * 4];
                #pragma unroll
                for (int qt = 0; qt < 2; ++qt)
                    o[qt][nt] = __builtin_amdgcn_mfma_f32_16x16x16f16(vv, pb[qt][mt], o[qt][nt], 0, 0, 0);
            }
        }
    }

    // epilogue
    #pragma unroll
    for (int qt = 0; qt < 2; ++qt) {
        float lq = lp[qt];
        lq += __shfl_xor(lq, 16); lq += __shfl_xor(lq, 32);
        float inv = 1.f / lq;
        int row = n0 + w * 32 + qt * 16 + c;
        if (row < NHW) {
            _Float16* op = ob + ((size_t)(b * NHW + row)) * ND + quad * 4;
            #pragma unroll
            for (int nt = 0; nt < 4; ++nt)
                pack4h(op + nt * 16, o[qt][nt][0] * inv, o[qt][nt][1] * inv,
                       o[qt][nt][2] * inv, o[qt][nt][3] * inv);
        }
    }
}

// ---------------- Kernel 3: proj + LN + MLP(gelu) + channel-mean (MFMA) ----------------
__global__ __launch_bounds__(TB) void k_post(
    const _Float16* __restrict__ aih,   // attn out f16 [B][N][64]
    const float* __restrict__ bp,
    const float* __restrict__ gm, const float* __restrict__ bm,
    const float* __restrict__ bm1,
    const _Float16* __restrict__ WpT, const _Float16* __restrict__ W1T,
    const float* __restrict__ w2bx,     // [65]: w2b + bm2b
    float* __restrict__ out)
{
    __shared__ _Float16 zL2[4 * 16 * 72];

    const int b = blockIdx.y, n0 = blockIdx.x * 64, tid = threadIdx.x;
    const int w = tid >> 6, lane = tid & 63, quad = lane >> 4, cl = lane & 15;
    const int tok = w * 16 + cl;

    const _Float16* ap = aih + ((size_t)(b * NHW + n0 + tok)) * ND;
    half8 ba[2];
    ba[0] = *(const half8*)(ap + quad * 8);
    ba[1] = *(const half8*)(ap + 32 + quad * 8);

    // u^T = WpT @ A^T (bias in acc)
    float uv[4][4];
    #pragma unroll
    for (int et = 0; et < 4; ++et) {
        float4 bq = *(const float4*)(bp + et * 16 + quad * 4);
        float4v acc = (float4v){bq.x, bq.y, bq.z, bq.w};
        #pragma unroll
        for (int ck = 0; ck < 2; ++ck) {
            half8 af = *(const half8*)(WpT + (et * 16 + cl) * 64 + ck * 32 + quad * 8);
            acc = __builtin_amdgcn_mfma_f32_16x16x32_f16(af, ba[ck], acc, 0, 0, 0);
        }
        #pragma unroll
        for (int r = 0; r < 4; ++r) uv[et][r] = acc[r];
    }

    // LayerNorm (gm, bm), in-lane
    {
        float sm = 0.f;
        #pragma unroll
        for (int et = 0; et < 4; ++et)
            #pragma unroll
            for (int r = 0; r < 4; ++r) sm += uv[et][r];
        sm += __shfl_xor(sm, 16); sm += __shfl_xor(sm, 32);
        const float mu = sm * (1.f / 64.f);
        float vr = 0.f;
        #pragma unroll
        for (int et = 0; et < 4; ++et)
            #pragma unroll
            for (int r = 0; r < 4; ++r) { float d = uv[et][r] - mu; vr += d * d; }
        vr += __shfl_xor(vr, 16); vr += __shfl_xor(vr, 32);
        const float is = rsqrtf(vr * (1.f / 64.f) + 1e-5f);
        #pragma unroll
        for (int et = 0; et < 4; ++et) {
            float4 gq = *(const float4*)(gm + et * 16 + quad * 4);
            float4 bq = *(const float4*)(bm + et * 16 + quad * 4);
            const float* gqp = (const float*)&gq;
            const float* bqp = (const float*)&bq;
            #pragma unroll
            for (int r = 0; r < 4; ++r)
                uv[et][r] = (uv[et][r] - mu) * is * gqp[r] + bqp[r];
        }
    }

    // stage z2 wave-private; B-frags
    _Float16* zw = zL2 + w * (16 * 72);
    #pragma unroll
    for (int et = 0; et < 4; ++et)
        *(half4*)&zw[cl * 72 + et * 16 + quad * 4] = pack4v(uv[et][0], uv[et][1], uv[et][2], uv[et][3]);
    __asm__ __volatile__("s_waitcnt lgkmcnt(0)" ::: "memory");
    half8 bz[2];
    #pragma unroll
    for (int ck = 0; ck < 2; ++ck)
        bz[ck] = *(const half8*)&zw[cl * 72 + ck * 32 + quad * 8];

    // h^T = W1T @ z2^T + bm1; gelu; dot with w2b; reduce
    float part = 0.f;
    #pragma unroll
    for (int et = 0; et < 4; ++et) {
        float4 b1q = *(const float4*)(bm1 + et * 16 + quad * 4);
        float4v acc = (float4v){b1q.x, b1q.y, b1q.z, b1q.w};
        #pragma unroll
        for (int ck = 0; ck < 2; ++ck) {
            half8 af = *(const half8*)(W1T + (et * 16 + cl) * 64 + ck * 32 + quad * 8);
            acc = __builtin_amdgcn_mfma_f32_16x16x32_f16(af, bz[ck], acc, 0, 0, 0);
        }
        float4 wq = *(const float4*)(w2bx + et * 16 + quad * 4);
        const float* wqp = (const float*)&wq;
        #pragma unroll
        for (int r = 0; r < 4; ++r) {
            float h = acc[r];
            float g = 0.5f * h * (1.f + erff(h * 0.70710678118654752f));
            part = fmaf(g, wqp[r], part);
        }
    }
    part += __shfl_xor(part, 16); part += __shfl_xor(part, 32);
    if (lane < 16)
        out[(size_t)b * NHW + n0 + tok] = part + w2bx[64];
}

extern "C" void kernel_launch(void* const* d_in, const int* in_sizes, int n_in,
                              void* d_out, int out_size, void* d_ws, size_t ws_size,
                              hipStream_t stream) {
    (void)in_sizes; (void)n_in; (void)out_size; (void)ws_size;
    const float* x    = (const float*)d_in[0];
    const float* We   = (const float*)d_in[1];
    const float* be   = (const float*)d_in[2];
    const float* g1   = (const float*)d_in[3];
    const float* b1   = (const float*)d_in[4];
    const float* g2   = (const float*)d_in[5];
    const float* b2   = (const float*)d_in[6];
    const float* Wqkv = (const float*)d_in[7];
    const float* bqkv = (const float*)d_in[8];
    const float* Wp   = (const float*)d_in[9];
    const float* bp   = (const float*)d_in[10];
    const float* gm   = (const float*)d_in[11];
    const float* bm   = (const float*)d_in[12];
    const float* W1   = (const float*)d_in[13];
    const float* bm1  = (const float*)d_in[14];
    const float* W2   = (const float*)d_in[15];
    const float* bm2  = (const float*)d_in[16];
    float* out = (float*)d_out;

    const size_t NQ = (size_t)NB * NHW * ND;
    _Float16* qh    = (_Float16*)d_ws;
    _Float16* khb   = qh + NQ;
    _Float16* vtb   = khb + NQ;
    _Float16* obf   = vtb + NQ;
    _Float16* WeT   = obf + NQ;
    _Float16* WqkvT = WeT + 64 * 128;
    _Float16* WpT   = WqkvT + 192 * 64;
    _Float16* W1T   = WpT + 64 * 64;
    float*    w2bx  = (float*)(W1T + 64 * 64);

    dim3 blk(TB);
    k_prep<<<dim3(8), blk, 0, stream>>>(We, Wqkv, Wp, W1, W2, bm2, WeT, WqkvT, WpT, W1T, w2bx);
    k_embed_qkv<<<dim3(NT, NB), blk, 0, stream>>>(x, be, g1, b1, g2, b2, bqkv, WeT, WqkvT, qh, khb, vtb);
    k_attn<<<dim3(25, NB), blk, 0, stream>>>(qh, khb, vtb, obf);
    k_post<<<dim3(NT, NB), blk, 0, stream>>>(obf, bp, gm, bm, bm1, WpT, W1T, w2bx, out);
}